// Round 1
// baseline (1105.727 us; speedup 1.0000x reference)
//
#include <hip/hip_runtime.h>

#define D 64

// ---------------- layer-0 init: embs[node][0][:] = concat(user_emb, item_emb) ----
__global__ void init_emb_kernel(const float4* __restrict__ ue, const float4* __restrict__ ie,
                                float4* __restrict__ embs, int n_users, int n) {
    int idx  = blockIdx.x * blockDim.x + threadIdx.x;     // over n*16 float4s
    int node = idx >> 4, q = idx & 15;
    if (node >= n) return;
    float4 v = (node < n_users) ? ue[node * 16 + q] : ie[(node - n_users) * 16 + q];
    embs[(size_t)node * 64 + q] = v;                      // node stride = 256 floats = 64 float4
}

// ---------------- CSR build ------------------------------------------------------
__global__ void hist_kernel(const int* __restrict__ row, int* __restrict__ counts, int m) {
    int i = blockIdx.x * blockDim.x + threadIdx.x;
    if (i < m) atomicAdd(&counts[row[i]], 1);
}

__global__ void blocksum_kernel(const int* __restrict__ counts, int* __restrict__ bsum, int n) {
    __shared__ int s[256];
    int t = threadIdx.x;
    int i = blockIdx.x * 256 + t;
    s[t] = (i < n) ? counts[i] : 0;
    __syncthreads();
    for (int d = 128; d > 0; d >>= 1) {
        if (t < d) s[t] += s[t + d];
        __syncthreads();
    }
    if (t == 0) bsum[blockIdx.x] = s[0];
}

// single block, 1024 threads; nb <= 1024 (nb = ceil(150000/256) = 586)
__global__ void scanb_kernel(const int* __restrict__ bsum, int* __restrict__ boff, int nb) {
    __shared__ int s[1024];
    int t = threadIdx.x;
    int v = (t < nb) ? bsum[t] : 0;
    s[t] = v;
    for (int d = 1; d < 1024; d <<= 1) {
        __syncthreads();
        int add = (t >= d) ? s[t - d] : 0;
        __syncthreads();
        s[t] += add;
    }
    __syncthreads();
    if (t < nb) boff[t] = s[t] - v;   // exclusive
}

// in-place: counts -> exclusive offsets; also init cursors
__global__ void final_kernel(int* __restrict__ offs, int* __restrict__ cursors,
                             const int* __restrict__ boff, int n, int total) {
    __shared__ int s[256];
    int t = threadIdx.x;
    int i = blockIdx.x * 256 + t;
    int v = (i < n) ? offs[i] : 0;
    s[t] = v;
    for (int d = 1; d < 256; d <<= 1) {
        __syncthreads();
        int add = (t >= d) ? s[t - d] : 0;
        __syncthreads();
        s[t] += add;
    }
    __syncthreads();
    int excl = s[t] - v + boff[blockIdx.x];
    if (i < n) { offs[i] = excl; cursors[i] = excl; }
    if (i == 0) offs[n] = total;
}

__global__ void scatter_kernel(const int* __restrict__ row, const int* __restrict__ col,
                               const float* __restrict__ val, int* __restrict__ cursors,
                               int2* __restrict__ edges, int m) {
    int i = blockIdx.x * blockDim.x + threadIdx.x;
    if (i >= m) return;
    int r   = row[i];
    int pos = atomicAdd(&cursors[r], 1);
    edges[pos] = make_int2(col[i], __float_as_int(val[i]));
}

// ---------------- SpMM: one wave per row, lane = dim -----------------------------
// x = embs + (l-1)*64 (node stride 256 floats), y = embs + l*64
__global__ void spmm_kernel(const int* __restrict__ offs, const int2* __restrict__ edges,
                            const float* __restrict__ x, float* __restrict__ y, int n) {
    int wave = (int)((blockIdx.x * (size_t)blockDim.x + threadIdx.x) >> 6);
    int lane = threadIdx.x & 63;
    if (wave >= n) return;
    int beg = offs[wave], end = offs[wave + 1];
    float acc = 0.f;
    int j = beg;
    for (; j + 1 < end; j += 2) {           // 2-way unroll: overlap the two gather chains
        int2 e0 = edges[j];
        int2 e1 = edges[j + 1];
        acc += __int_as_float(e0.y) * x[(size_t)e0.x * 256 + lane];
        acc += __int_as_float(e1.y) * x[(size_t)e1.x * 256 + lane];
    }
    if (j < end) {
        int2 e = edges[j];
        acc += __int_as_float(e.y) * x[(size_t)e.x * 256 + lane];
    }
    y[(size_t)wave * 256 + lane] = acc;
}

// ---------------- mean over 4 layers -> users / items ----------------------------
__global__ void mean_kernel(const float4* __restrict__ embs, float4* __restrict__ users,
                            float4* __restrict__ items, int n_users, int n) {
    int idx  = blockIdx.x * blockDim.x + threadIdx.x;     // over n*16 float4s
    int node = idx >> 4, q = idx & 15;
    if (node >= n) return;
    const float4* p = embs + (size_t)node * 64 + q;
    float4 a = p[0], b = p[16], c = p[32], d = p[48];
    float4 mv;
    mv.x = (a.x + b.x + c.x + d.x) * 0.25f;
    mv.y = (a.y + b.y + c.y + d.y) * 0.25f;
    mv.z = (a.z + b.z + c.z + d.z) * 0.25f;
    mv.w = (a.w + b.w + c.w + d.w) * 0.25f;
    if (node < n_users) users[node * 16 + q] = mv;
    else                items[(node - n_users) * 16 + q] = mv;
}

extern "C" void kernel_launch(void* const* d_in, const int* in_sizes, int n_in,
                              void* d_out, int out_size, void* d_ws, size_t ws_size,
                              hipStream_t stream) {
    const float* user_emb = (const float*)d_in[0];
    const float* item_emb = (const float*)d_in[1];
    const int*   edge_row = (const int*)d_in[2];
    const int*   edge_col = (const int*)d_in[3];
    const float* edge_val = (const float*)d_in[4];

    const int n_users = in_sizes[0] / D;
    const int n_items = in_sizes[1] / D;
    const int n       = n_users + n_items;
    const int m       = in_sizes[2];

    float* out_users = (float*)d_out;                       // (n_users, 64)
    float* out_items = out_users + (size_t)n_users * D;     // (n_items, 64)
    float* embs      = out_items + (size_t)n_items * D;     // (n, 4, 64)

    // workspace carve-up
    char* ws = (char*)d_ws;
    int*  offs    = (int*)ws;                // n+1 (counts -> offsets, in place)
    int*  cursors = offs + (n + 1);          // n
    const int nb  = (n + 255) / 256;         // 586 for n=150000 (must be <= 1024)
    int*  bsum    = cursors + n;             // nb
    int*  boff    = bsum + nb;               // nb
    size_t int_bytes = ((size_t)(n + 1) + n + nb + nb) * sizeof(int);
    size_t edge_off  = (int_bytes + 15) & ~(size_t)15;
    int2* cedges = (int2*)(ws + edge_off);   // m pairs (col, val) in row-sorted order

    // 1. zero counts
    hipMemsetAsync(offs, 0, (size_t)n * sizeof(int), stream);

    // 2. layer-0 embeddings straight into d_out's embs region
    init_emb_kernel<<<(n * 16 + 255) / 256, 256, 0, stream>>>(
        (const float4*)user_emb, (const float4*)item_emb, (float4*)embs, n_users, n);

    // 3. CSR build
    hist_kernel<<<(m + 255) / 256, 256, 0, stream>>>(edge_row, offs, m);
    blocksum_kernel<<<nb, 256, 0, stream>>>(offs, bsum, n);
    scanb_kernel<<<1, 1024, 0, stream>>>(bsum, boff, nb);
    final_kernel<<<nb, 256, 0, stream>>>(offs, cursors, boff, n, m);
    scatter_kernel<<<(m + 255) / 256, 256, 0, stream>>>(edge_row, edge_col, edge_val,
                                                        cursors, cedges, m);

    // 4. three propagation layers (gather-SpMM, no fp32 atomics)
    for (int l = 1; l <= 3; ++l) {
        spmm_kernel<<<(n + 3) / 4, 256, 0, stream>>>(offs, cedges,
                                                     embs + (size_t)(l - 1) * D,
                                                     embs + (size_t)l * D, n);
    }

    // 5. layer mean -> users / items
    mean_kernel<<<(n * 16 + 255) / 256, 256, 0, stream>>>(
        (const float4*)embs, (float4*)out_users, (float4*)out_items, n_users, n);
}